// Round 25
// baseline (65.887 us; speedup 1.0000x reference)
//
#include <hip/hip_runtime.h>
#include <hip/hip_bf16.h>

#define DIM   512
#define NHEAD 8
#define DM    64
#define DL    128
#define BBAG  8
#define NINST 4096
#define MTOT  (BBAG*NINST)     // 32768 instances
#define BM    32
#define NBLK  (MTOT/BM)        // 1024 fused blocks
#define CPB   (NBLK/BBAG)      // 128 chunks per bag

typedef short   bf16x8 __attribute__((ext_vector_type(8)));
typedef __bf16  bf16v8 __attribute__((ext_vector_type(8)));
typedef float   f32x4  __attribute__((ext_vector_type(4)));
typedef short   s16x4  __attribute__((ext_vector_type(4)));

__device__ __forceinline__ short f2b(float f) {
  __hip_bfloat16 h = __float2bfloat16(f);
  return __builtin_bit_cast(short, h);
}
__device__ __forceinline__ float b2f(short s) {
  __hip_bfloat16 h = __builtin_bit_cast(__hip_bfloat16, s);
  return __bfloat162float(h);
}
__device__ __forceinline__ f32x4 mfma_bf16(bf16x8 a, bf16x8 b, f32x4 c) {
  return __builtin_amdgcn_mfma_f32_16x16x32_bf16(
      __builtin_bit_cast(bf16v8, a), __builtin_bit_cast(bf16v8, b), c, 0, 0, 0);
}
__device__ __forceinline__ float fast_tanh(float x) {
  float t = __expf(2.0f * x);
  return 1.0f - 2.0f * __builtin_amdgcn_rcpf(t + 1.0f);
}
__device__ __forceinline__ float fast_sigmoid(float x) {
  return __builtin_amdgcn_rcpf(1.0f + __expf(-x));
}

// ---------------------------------------------------------------------------
// Kernel 1: build Wt2 (proj B, pre-swizzled slabs) and Vt_f (fragment-packed
// score B). Validated on HW (R16-R24, absmax 7.6e-6). Unchanged.
// ---------------------------------------------------------------------------
__global__ __launch_bounds__(256) void prep_weights(
    const float* __restrict__ WX, const float* __restrict__ V,
    const float* __restrict__ gate_w,
    short* __restrict__ Wt2, short* __restrict__ Vt_f) {
  __shared__ float lds[32 * 129];
  const int bid = blockIdx.x, t = threadIdx.x;

  if (bid < 128) {
    const int h = bid >> 4, ks = bid & 15;
    {
      const int kl = t >> 3, m8 = (t & 7) * 8;
      const float* src = WX + ((size_t)(h * DIM + ks * 32 + kl) * DM + m8);
      #pragma unroll
      for (int j = 0; j < 8; ++j) lds[kl * 129 + m8 + j] = src[j];
    }
    __syncthreads();
    {
      const int m = t >> 2, q = t & 3;
      const int col = h * 64 + m;
      const int q2 = (q + ((col & 15) >> 1)) & 3;
      short* dst = Wt2 + ks * 20480 + col * 32 + q2 * 8;
      #pragma unroll
      for (int j = 0; j < 8; ++j) dst[j] = f2b(lds[(q * 8 + j) * 129 + m]);
    }
  } else if (bid < 144) {
    const int ks = bid - 128;
    #pragma unroll
    for (int rep = 0; rep < 2; ++rep) {
      const int idx = rep * 2048 + t * 8;
      const int kl = idx >> 7, l8 = idx & 127;
      const float* src = gate_w + ((size_t)(ks * 32 + kl) * DL + l8);
      #pragma unroll
      for (int j = 0; j < 8; ++j) lds[kl * 129 + l8 + j] = src[j];
    }
    __syncthreads();
    #pragma unroll
    for (int rep = 0; rep < 2; ++rep) {
      const int piece = rep * 256 + t;
      const int l = piece >> 2, q = piece & 3;
      const int col = 512 + l;
      const int q2 = (q + ((col & 15) >> 1)) & 3;
      short* dst = Wt2 + ks * 20480 + col * 32 + q2 * 8;
      #pragma unroll
      for (int j = 0; j < 8; ++j) dst[j] = f2b(lds[(q * 8 + j) * 129 + l]);
    }
  } else {
    // Vt_f: entry e = (ct*2+half)*64 + lane; holds V[m=half*32+q*8+j][l=16ct+r]
    #pragma unroll
    for (int rep = 0; rep < 4; ++rep) {
      const int e = t + rep * 256;
      const int ct = e >> 7, half = (e >> 6) & 1, lane = e & 63;
      const int r = lane & 15, q = lane >> 4;
      short* dst = Vt_f + (size_t)e * 8;
      #pragma unroll
      for (int j = 0; j < 8; ++j) {
        const int m = half * 32 + q * 8 + j;
        dst[j] = f2b(V[(size_t)m * DL + ct * 16 + r]);
      }
    }
  }
}

// ---------------------------------------------------------------------------
// Kernel 2 (FUSED, BM=32, 2 blocks/CU) = R21/R24 empirical best, plus:
//  * T5 s_setprio(1/0) around MFMA clusters — waves are fully desynced
//    (no K-loop barriers), matching T5's "wave role diversity" regime
//    (guide m191: +4-7% in that regime; null only for lockstep m190).
//  * T14 micro-hoist: wc[8] + first Vt_f fragment pair issued BEFORE the
//    epilogue barrier (global loads independent of LDS phase).
// ---------------------------------------------------------------------------
#define BLOAD(dst, addr) \
  asm volatile("global_load_dwordx4 %0, %1, off" : "=v"(dst) : "v"(addr))

__global__ __launch_bounds__(512, 4) void fused_kernel(
    const float* __restrict__ x, const short* __restrict__ Wt2,
    const short* __restrict__ Vt_f, const float* __restrict__ W,
    const int* __restrict__ true_num,
    float* __restrict__ part, float* __restrict__ esum,
    float* __restrict__ e0) {
  __shared__ alignas(16) short lds[18432];   // 36,864 B
  const int tid = threadIdx.x;
  const int blk = blockIdx.x;
  const int bm0 = blk * BM;
  const int lane = tid & 63;
  const int w = tid >> 6;            // wave 0..7 -> cols [80w,80w+80); head w
  const int r = lane & 15;
  const int q = lane >> 4;           // 0..3
  const int swzs = (q + (r >> 1)) & 3;
  char* lda = reinterpret_cast<char*>(lds);
  char* mh_base = reinterpret_cast<char*>(lds);          // [32][1024B] swizzled
  short* gate_lds = lds + 16384;                         // 16 tiles*64 lanes*4

  const int tn = true_num[blk >> 7];          // bag = blk/128
  const int nbase = bm0 & (NINST - 1);        // row offset within bag

  // ---- phase 1: stage A tile (32 x 512) f32 -> bf16 LDS, swizzled ----
  {
    const int arow = tid >> 4, ap = tid & 15;
    const int aslot = ((ap >> 2) + ((arow & 15) >> 1)) & 3;
    const float* asrc = x + ((size_t)(bm0 + arow) << 9) + ap * 2;
    char* adst = lda + arow * 64 + aslot * 16 + (ap & 3) * 4;
    #pragma unroll
    for (int ks = 0; ks < 16; ++ks) {
      float2 v = *reinterpret_cast<const float2*>(asrc + ks * 32);
      unsigned pk = ((unsigned)(unsigned short)f2b(v.y) << 16) |
                    (unsigned)(unsigned short)f2b(v.x);
      *reinterpret_cast<unsigned*>(adst + ks * 2048) = pk;
    }
  }
  __syncthreads();   // drains prologue vmem; asm ledger starts at 0

  const short* bbase = Wt2 + (80 * w + r) * 32 + swzs * 8;
  bf16x8 bufs[2][5];
  #pragma unroll
  for (int ct = 0; ct < 5; ++ct) BLOAD(bufs[0][ct], bbase + 0 * 20480 + ct * 512);
  #pragma unroll
  for (int ct = 0; ct < 5; ++ct) BLOAD(bufs[1][ct], bbase + 1 * 20480 + ct * 512);

  const int aoff = r * 64 + swzs * 16;
  bf16x8 afb[2][2];
  #pragma unroll
  for (int rt = 0; rt < 2; ++rt)
    afb[0][rt] = *reinterpret_cast<const bf16x8*>(lda + 0 * 2048 + aoff + rt * 1024);

  f32x4 acc[2][5];
  #pragma unroll
  for (int rt = 0; rt < 2; ++rt)
    #pragma unroll
    for (int ct = 0; ct < 5; ++ct) acc[rt][ct] = f32x4{0.f, 0.f, 0.f, 0.f};

  #pragma unroll
  for (int ks = 0; ks < 16; ++ks) {
    // retire B(ks); B(ks+1) stays in flight
    if (ks < 15) asm volatile("s_waitcnt vmcnt(5)" ::: "memory");
    else         asm volatile("s_waitcnt vmcnt(0)" ::: "memory");
    __builtin_amdgcn_sched_barrier(0);

    if (ks + 1 < 16) {
      #pragma unroll
      for (int rt = 0; rt < 2; ++rt)
        afb[(ks + 1) & 1][rt] = *reinterpret_cast<const bf16x8*>(
            lda + (ks + 1) * 2048 + aoff + rt * 1024);
    }
    __builtin_amdgcn_s_setprio(1);                 // T5: favor MFMA cluster
    #pragma unroll
    for (int ct = 0; ct < 5; ++ct)
      #pragma unroll
      for (int rt = 0; rt < 2; ++rt)
        acc[rt][ct] = mfma_bf16(afb[ks & 1][rt], bufs[ks & 1][ct], acc[rt][ct]);
    __builtin_amdgcn_s_setprio(0);
    // refill the just-consumed buffer with B(ks+2) (WAR-safe: issued after reads)
    if (ks + 2 < 16) {
      #pragma unroll
      for (int ct = 0; ct < 5; ++ct)
        BLOAD(bufs[ks & 1][ct], bbase + (ks + 2) * 20480 + ct * 512);
    }
  }

  // T14 micro-hoist: issue score-phase globals before the barrier (L2-hot,
  // independent of LDS phase; latency hides under epilogue+barrier).
  const int h = w;
  float wc[8];
  #pragma unroll
  for (int lt = 0; lt < 8; ++lt) wc[lt] = W[(size_t)h * DL + 16 * lt + r];
  bf16x8 vb0 = *reinterpret_cast<const bf16x8*>(Vt_f + (size_t)0 * 512 + lane * 8);
  bf16x8 vb1 = *reinterpret_cast<const bf16x8*>(Vt_f + (size_t)1 * 512 + lane * 8);

  __syncthreads();   // all A reads done; safe to overwrite with mh/gate

  // ---- epilogue: mh -> swizzled LDS [32][1024B]; gate -> fragment tiles ----
  #pragma unroll
  for (int rt = 0; rt < 2; ++rt) {
    #pragma unroll
    for (int ct = 0; ct < 5; ++ct) {
      const int colbase = 80 * w + 16 * ct;
      if (colbase < NHEAD * DM) {
        const int col = colbase + r;
        #pragma unroll
        for (int j = 0; j < 4; ++j) {
          const int row = 16 * rt + 4 * q + j;
          const int intra = (col * 2) ^ ((row & 7) << 4);
          *reinterpret_cast<short*>(mh_base + row * 1024 + intra) =
              f2b(acc[rt][ct][j]);
        }
      } else {
        const int ltile = 5 * w + ct - 32;
        s16x4 gv;
        gv.x = f2b(fast_sigmoid(acc[rt][ct][0]));
        gv.y = f2b(fast_sigmoid(acc[rt][ct][1]));
        gv.z = f2b(fast_sigmoid(acc[rt][ct][2]));
        gv.w = f2b(fast_sigmoid(acc[rt][ct][3]));
        *reinterpret_cast<s16x4*>(
            gate_lds + ((rt * 8 + ltile) * 64 + lane) * 4) = gv;
      }
    }
  }
  __syncthreads();   // mh + gate complete

  // ---- score phase: wave w = head h = w, 32 rows ----
  bf16x8 a0[2], a1[2];
  #pragma unroll
  for (int rt = 0; rt < 2; ++rt) {
    const int row = 16 * rt + r;
    const int swz = (row & 7) << 4;
    a0[rt] = *reinterpret_cast<const bf16x8*>(
        mh_base + row * 1024 + ((h * 128 + q * 16) ^ swz));
    a1[rt] = *reinterpret_cast<const bf16x8*>(
        mh_base + row * 1024 + ((h * 128 + q * 16 + 64) ^ swz));
  }

  float sc[2][4];
  #pragma unroll
  for (int rt = 0; rt < 2; ++rt)
    #pragma unroll
    for (int j = 0; j < 4; ++j) sc[rt][j] = 0.f;

  #pragma unroll
  for (int lt = 0; lt < 8; ++lt) {
    bf16x8 b0 = (lt == 0) ? vb0 : *reinterpret_cast<const bf16x8*>(
        Vt_f + (size_t)(lt * 2) * 512 + lane * 8);
    bf16x8 b1 = (lt == 0) ? vb1 : *reinterpret_cast<const bf16x8*>(
        Vt_f + (size_t)(lt * 2 + 1) * 512 + lane * 8);
    #pragma unroll
    for (int rt = 0; rt < 2; ++rt) {
      f32x4 t = f32x4{0.f, 0.f, 0.f, 0.f};
      __builtin_amdgcn_s_setprio(1);               // T5: score MFMA pair
      t = mfma_bf16(a0[rt], b0, t);
      t = mfma_bf16(a1[rt], b1, t);
      __builtin_amdgcn_s_setprio(0);
      s16x4 ga = *reinterpret_cast<const s16x4*>(
          gate_lds + ((rt * 8 + lt) * 64 + lane) * 4);
      #pragma unroll
      for (int j = 0; j < 4; ++j) {
        float g = b2f((j == 0) ? ga.x : (j == 1) ? ga.y : (j == 2) ? ga.z : ga.w);
        sc[rt][j] += fast_tanh(t[j]) * g * wc[lt];
      }
    }
  }

  float evals[2] = {0.f, 0.f};
  float epart = 0.f;
  #pragma unroll
  for (int rt = 0; rt < 2; ++rt) {
    #pragma unroll
    for (int j = 0; j < 4; ++j) {
      sc[rt][j] += __shfl_xor(sc[rt][j], 1);
      sc[rt][j] += __shfl_xor(sc[rt][j], 2);
      sc[rt][j] += __shfl_xor(sc[rt][j], 4);
      sc[rt][j] += __shfl_xor(sc[rt][j], 8);
    }
    if (r < 4) {
      const int row = 16 * rt + 4 * q + r;
      float s = (r == 0) ? sc[rt][0] : (r == 1) ? sc[rt][1]
              : (r == 2) ? sc[rt][2] : sc[rt][3];
      float e = (nbase + row < tn) ? __expf(s) : 0.0f;
      evals[rt] = e;
      epart += e;
      if (w == 0) e0[bm0 + row] = e;       // head-0 numerators
    }
  }
  #pragma unroll
  for (int m = 1; m < 64; m <<= 1) epart += __shfl_xor(epart, m);
  if (lane == 0) esum[(size_t)h * NBLK + blk] = epart;

  // ---- pool phase: P[m=lane] = sum over 32 rows of e*mh ----
  {
    float P = 0.f;
    #pragma unroll
    for (int rt = 0; rt < 2; ++rt) {
      #pragma unroll
      for (int rr = 0; rr < 16; ++rr) {
        const int row = 16 * rt + rr;
        const float ev = __shfl(evals[rt], 16 * (rr >> 2) + (rr & 3));
        const int intra = (h * 128 + lane * 2) ^ ((row & 7) << 4);
        P += ev * b2f(*reinterpret_cast<const short*>(mh_base + row * 1024 + intra));
      }
    }
    part[((size_t)h * NBLK + blk) * 64 + lane] = P;
  }
}

// ---------------------------------------------------------------------------
// Kernel 3: finalize. grid 64 = (h,b); 128 chunks per bag. Unchanged.
// ---------------------------------------------------------------------------
__global__ __launch_bounds__(256) void finalize_kernel(
    const float* __restrict__ part, const float* __restrict__ esum,
    const float* __restrict__ e0,
    float* __restrict__ out_feat, float* __restrict__ out_soft) {
  const int h = blockIdx.x >> 3, b = blockIdx.x & 7;
  const int tid = threadIdx.x;

  float Z = 0.f;
  #pragma unroll 8
  for (int c = 0; c < CPB; ++c) Z += esum[(size_t)h * NBLK + b * CPB + c];
  const float invZ = 1.0f / Z;

  if (tid < 64) {
    float s = 0.f;
    #pragma unroll 8
    for (int c = 0; c < CPB; ++c)
      s += part[((size_t)h * NBLK + b * CPB + c) * 64 + tid];
    out_feat[(size_t)b * (NHEAD * DM) + h * DM + tid] = s * invZ;
  }
  if (h == 0) {
    #pragma unroll
    for (int i = 0; i < 16; ++i) {
      const int n = tid + i * 256;
      out_soft[(size_t)b * NINST + n] = e0[(size_t)b * NINST + n] * invZ;
    }
  }
}

// ---------------------------------------------------------------------------
extern "C" void kernel_launch(void* const* d_in, const int* in_sizes, int n_in,
                              void* d_out, int out_size, void* d_ws, size_t ws_size,
                              hipStream_t stream) {
  (void)in_sizes; (void)n_in; (void)out_size; (void)ws_size;
  const float* x      = (const float*)d_in[0];
  const float* WX     = (const float*)d_in[1];
  const float* V      = (const float*)d_in[2];
  const float* W      = (const float*)d_in[3];
  const float* gate_w = (const float*)d_in[4];
  const int* true_num = (const int*)d_in[5];
  float* out = (float*)d_out;

  char* ws = (char*)d_ws;
  short* Wt2  = (short*)ws;  ws += (size_t)(NHEAD * DM + DL) * DIM * 2; //   655,360 B
  short* Vt_f = (short*)ws;  ws += (size_t)DL * DM * 2;                 //    16,384 B
  float* part = (float*)ws;  ws += (size_t)NHEAD * NBLK * 64 * 4;       // 2,097,152 B
  float* esum = (float*)ws;  ws += (size_t)NHEAD * NBLK * 4;            //    32,768 B
  float* e0   = (float*)ws;  ws += (size_t)MTOT * 4;                    //   131,072 B

  prep_weights<<<dim3(145), dim3(256), 0, stream>>>(WX, V, gate_w, Wt2, Vt_f);
  fused_kernel<<<dim3(NBLK), dim3(512), 0, stream>>>(
      x, Wt2, Vt_f, W, true_num, part, esum, e0);
  finalize_kernel<<<dim3(NHEAD * BBAG), dim3(256), 0, stream>>>(
      part, esum, e0, out, out + BBAG * NHEAD * DM);
}

// Round 26
// 64.642 us; speedup vs baseline: 1.0193x; 1.0193x over previous
//
#include <hip/hip_runtime.h>
#include <hip/hip_bf16.h>

#define DIM   512
#define NHEAD 8
#define DM    64
#define DL    128
#define BBAG  8
#define NINST 4096
#define MTOT  (BBAG*NINST)     // 32768 instances
#define BM    32
#define NBLK  (MTOT/BM)        // 1024 fused blocks
#define CPB   (NBLK/BBAG)      // 128 chunks per bag

typedef short   bf16x8 __attribute__((ext_vector_type(8)));
typedef __bf16  bf16v8 __attribute__((ext_vector_type(8)));
typedef float   f32x4  __attribute__((ext_vector_type(4)));
typedef short   s16x4  __attribute__((ext_vector_type(4)));

__device__ __forceinline__ short f2b(float f) {
  __hip_bfloat16 h = __float2bfloat16(f);
  return __builtin_bit_cast(short, h);
}
__device__ __forceinline__ float b2f(short s) {
  __hip_bfloat16 h = __builtin_bit_cast(__hip_bfloat16, s);
  return __bfloat162float(h);
}
__device__ __forceinline__ f32x4 mfma_bf16(bf16x8 a, bf16x8 b, f32x4 c) {
  return __builtin_amdgcn_mfma_f32_16x16x32_bf16(
      __builtin_bit_cast(bf16v8, a), __builtin_bit_cast(bf16v8, b), c, 0, 0, 0);
}
__device__ __forceinline__ float fast_sigmoid(float x) {
  return __builtin_amdgcn_rcpf(1.0f + __expf(-x));
}
__device__ __forceinline__ float fast_tanh(float x) {
  float t = __expf(2.0f * x);
  return 1.0f - 2.0f * __builtin_amdgcn_rcpf(t + 1.0f);
}

// ---------------------------------------------------------------------------
// Kernel 1: build Wt2 (proj B, pre-swizzled slabs) and Vt_f (fragment-packed
// score B). Validated on HW (R16-R25, absmax 7.6e-6).
// ---------------------------------------------------------------------------
__global__ __launch_bounds__(256) void prep_weights(
    const float* __restrict__ WX, const float* __restrict__ V,
    const float* __restrict__ gate_w,
    short* __restrict__ Wt2, short* __restrict__ Vt_f) {
  __shared__ float lds[32 * 129];
  const int bid = blockIdx.x, t = threadIdx.x;

  if (bid < 128) {
    const int h = bid >> 4, ks = bid & 15;
    {
      const int kl = t >> 3, m8 = (t & 7) * 8;
      const float* src = WX + ((size_t)(h * DIM + ks * 32 + kl) * DM + m8);
      #pragma unroll
      for (int j = 0; j < 8; ++j) lds[kl * 129 + m8 + j] = src[j];
    }
    __syncthreads();
    {
      const int m = t >> 2, q = t & 3;
      const int col = h * 64 + m;
      const int q2 = (q + ((col & 15) >> 1)) & 3;
      short* dst = Wt2 + ks * 20480 + col * 32 + q2 * 8;
      #pragma unroll
      for (int j = 0; j < 8; ++j) dst[j] = f2b(lds[(q * 8 + j) * 129 + m]);
    }
  } else if (bid < 144) {
    const int ks = bid - 128;
    #pragma unroll
    for (int rep = 0; rep < 2; ++rep) {
      const int idx = rep * 2048 + t * 8;
      const int kl = idx >> 7, l8 = idx & 127;
      const float* src = gate_w + ((size_t)(ks * 32 + kl) * DL + l8);
      #pragma unroll
      for (int j = 0; j < 8; ++j) lds[kl * 129 + l8 + j] = src[j];
    }
    __syncthreads();
    #pragma unroll
    for (int rep = 0; rep < 2; ++rep) {
      const int piece = rep * 256 + t;
      const int l = piece >> 2, q = piece & 3;
      const int col = 512 + l;
      const int q2 = (q + ((col & 15) >> 1)) & 3;
      short* dst = Wt2 + ks * 20480 + col * 32 + q2 * 8;
      #pragma unroll
      for (int j = 0; j < 8; ++j) dst[j] = f2b(lds[(q * 8 + j) * 129 + l]);
    }
  } else {
    // Vt_f: entry e = (ct*2+half)*64 + lane; holds V[m=half*32+q*8+j][l=16ct+r]
    #pragma unroll
    for (int rep = 0; rep < 4; ++rep) {
      const int e = t + rep * 256;
      const int ct = e >> 7, half = (e >> 6) & 1, lane = e & 63;
      const int r = lane & 15, q = lane >> 4;
      short* dst = Vt_f + (size_t)e * 8;
      #pragma unroll
      for (int j = 0; j < 8; ++j) {
        const int m = half * 32 + q * 8 + j;
        dst[j] = f2b(V[(size_t)m * DL + ct * 16 + r]);
      }
    }
  }
}

// ---------------------------------------------------------------------------
// Kernel 2 (FUSED, BM=32, 2 blocks/CU) — SESSION EMPIRICAL BEST (R21/R24):
// proj GEMM (asm-pinned depth-2 B reg pipeline, counted vmcnt, swizzled
// A-LDS) + score (fragment-packed Vt_f/gate in LDS) + masked softmax
// numerators (registers) + partial pool, all in one kernel; mh never
// touches global memory. 134 us naive -> 65 us.
// ---------------------------------------------------------------------------
#define BLOAD(dst, addr) \
  asm volatile("global_load_dwordx4 %0, %1, off" : "=v"(dst) : "v"(addr))

__global__ __launch_bounds__(512, 4) void fused_kernel(
    const float* __restrict__ x, const short* __restrict__ Wt2,
    const short* __restrict__ Vt_f, const float* __restrict__ W,
    const int* __restrict__ true_num,
    float* __restrict__ part, float* __restrict__ esum,
    float* __restrict__ e0) {
  __shared__ alignas(16) short lds[18432];   // 36,864 B
  const int tid = threadIdx.x;
  const int blk = blockIdx.x;
  const int bm0 = blk * BM;
  const int lane = tid & 63;
  const int w = tid >> 6;            // wave 0..7 -> cols [80w,80w+80); head w
  const int r = lane & 15;
  const int q = lane >> 4;           // 0..3
  const int swzs = (q + (r >> 1)) & 3;
  char* lda = reinterpret_cast<char*>(lds);
  char* mh_base = reinterpret_cast<char*>(lds);          // [32][1024B] swizzled
  short* gate_lds = lds + 16384;                         // 16 tiles*64 lanes*4

  const int tn = true_num[blk >> 7];          // bag = blk/128
  const int nbase = bm0 & (NINST - 1);        // row offset within bag

  // ---- phase 1: stage A tile (32 x 512) f32 -> bf16 LDS, swizzled ----
  {
    const int arow = tid >> 4, ap = tid & 15;
    const int aslot = ((ap >> 2) + ((arow & 15) >> 1)) & 3;
    const float* asrc = x + ((size_t)(bm0 + arow) << 9) + ap * 2;
    char* adst = lda + arow * 64 + aslot * 16 + (ap & 3) * 4;
    #pragma unroll
    for (int ks = 0; ks < 16; ++ks) {
      float2 v = *reinterpret_cast<const float2*>(asrc + ks * 32);
      unsigned pk = ((unsigned)(unsigned short)f2b(v.y) << 16) |
                    (unsigned)(unsigned short)f2b(v.x);
      *reinterpret_cast<unsigned*>(adst + ks * 2048) = pk;
    }
  }
  __syncthreads();   // drains prologue vmem; asm ledger starts at 0

  const short* bbase = Wt2 + (80 * w + r) * 32 + swzs * 8;
  bf16x8 bufs[2][5];
  #pragma unroll
  for (int ct = 0; ct < 5; ++ct) BLOAD(bufs[0][ct], bbase + 0 * 20480 + ct * 512);
  #pragma unroll
  for (int ct = 0; ct < 5; ++ct) BLOAD(bufs[1][ct], bbase + 1 * 20480 + ct * 512);

  const int aoff = r * 64 + swzs * 16;
  bf16x8 afb[2][2];
  #pragma unroll
  for (int rt = 0; rt < 2; ++rt)
    afb[0][rt] = *reinterpret_cast<const bf16x8*>(lda + 0 * 2048 + aoff + rt * 1024);

  f32x4 acc[2][5];
  #pragma unroll
  for (int rt = 0; rt < 2; ++rt)
    #pragma unroll
    for (int ct = 0; ct < 5; ++ct) acc[rt][ct] = f32x4{0.f, 0.f, 0.f, 0.f};

  #pragma unroll
  for (int ks = 0; ks < 16; ++ks) {
    // retire B(ks); B(ks+1) stays in flight
    if (ks < 15) asm volatile("s_waitcnt vmcnt(5)" ::: "memory");
    else         asm volatile("s_waitcnt vmcnt(0)" ::: "memory");
    __builtin_amdgcn_sched_barrier(0);

    if (ks + 1 < 16) {
      #pragma unroll
      for (int rt = 0; rt < 2; ++rt)
        afb[(ks + 1) & 1][rt] = *reinterpret_cast<const bf16x8*>(
            lda + (ks + 1) * 2048 + aoff + rt * 1024);
    }
    #pragma unroll
    for (int ct = 0; ct < 5; ++ct)
      #pragma unroll
      for (int rt = 0; rt < 2; ++rt)
        acc[rt][ct] = mfma_bf16(afb[ks & 1][rt], bufs[ks & 1][ct], acc[rt][ct]);
    // refill the just-consumed buffer with B(ks+2) (WAR-safe: issued after reads)
    if (ks + 2 < 16) {
      #pragma unroll
      for (int ct = 0; ct < 5; ++ct)
        BLOAD(bufs[ks & 1][ct], bbase + (ks + 2) * 20480 + ct * 512);
    }
  }

  __syncthreads();   // all A reads done; safe to overwrite with mh/gate

  // ---- epilogue: mh -> swizzled LDS [32][1024B]; gate -> fragment tiles ----
  #pragma unroll
  for (int rt = 0; rt < 2; ++rt) {
    #pragma unroll
    for (int ct = 0; ct < 5; ++ct) {
      const int colbase = 80 * w + 16 * ct;
      if (colbase < NHEAD * DM) {
        const int col = colbase + r;
        #pragma unroll
        for (int j = 0; j < 4; ++j) {
          const int row = 16 * rt + 4 * q + j;
          const int intra = (col * 2) ^ ((row & 7) << 4);
          *reinterpret_cast<short*>(mh_base + row * 1024 + intra) =
              f2b(acc[rt][ct][j]);
        }
      } else {
        const int ltile = 5 * w + ct - 32;
        s16x4 gv;
        gv.x = f2b(fast_sigmoid(acc[rt][ct][0]));
        gv.y = f2b(fast_sigmoid(acc[rt][ct][1]));
        gv.z = f2b(fast_sigmoid(acc[rt][ct][2]));
        gv.w = f2b(fast_sigmoid(acc[rt][ct][3]));
        *reinterpret_cast<s16x4*>(
            gate_lds + ((rt * 8 + ltile) * 64 + lane) * 4) = gv;
      }
    }
  }
  __syncthreads();   // mh + gate complete

  // ---- score phase: wave w = head h = w, 32 rows ----
  const int h = w;
  float wc[8];
  #pragma unroll
  for (int lt = 0; lt < 8; ++lt) wc[lt] = W[(size_t)h * DL + 16 * lt + r];

  bf16x8 a0[2], a1[2];
  #pragma unroll
  for (int rt = 0; rt < 2; ++rt) {
    const int row = 16 * rt + r;
    const int swz = (row & 7) << 4;
    a0[rt] = *reinterpret_cast<const bf16x8*>(
        mh_base + row * 1024 + ((h * 128 + q * 16) ^ swz));
    a1[rt] = *reinterpret_cast<const bf16x8*>(
        mh_base + row * 1024 + ((h * 128 + q * 16 + 64) ^ swz));
  }

  float sc[2][4];
  #pragma unroll
  for (int rt = 0; rt < 2; ++rt)
    #pragma unroll
    for (int j = 0; j < 4; ++j) sc[rt][j] = 0.f;

  #pragma unroll
  for (int lt = 0; lt < 8; ++lt) {
    bf16x8 b0 = *reinterpret_cast<const bf16x8*>(Vt_f + (size_t)(lt * 2) * 512 + lane * 8);
    bf16x8 b1 = *reinterpret_cast<const bf16x8*>(Vt_f + (size_t)(lt * 2 + 1) * 512 + lane * 8);
    #pragma unroll
    for (int rt = 0; rt < 2; ++rt) {
      f32x4 t = f32x4{0.f, 0.f, 0.f, 0.f};
      t = mfma_bf16(a0[rt], b0, t);
      t = mfma_bf16(a1[rt], b1, t);
      s16x4 ga = *reinterpret_cast<const s16x4*>(
          gate_lds + ((rt * 8 + lt) * 64 + lane) * 4);
      #pragma unroll
      for (int j = 0; j < 4; ++j) {
        float g = b2f((j == 0) ? ga.x : (j == 1) ? ga.y : (j == 2) ? ga.z : ga.w);
        sc[rt][j] += fast_tanh(t[j]) * g * wc[lt];
      }
    }
  }

  float evals[2] = {0.f, 0.f};
  float epart = 0.f;
  #pragma unroll
  for (int rt = 0; rt < 2; ++rt) {
    #pragma unroll
    for (int j = 0; j < 4; ++j) {
      sc[rt][j] += __shfl_xor(sc[rt][j], 1);
      sc[rt][j] += __shfl_xor(sc[rt][j], 2);
      sc[rt][j] += __shfl_xor(sc[rt][j], 4);
      sc[rt][j] += __shfl_xor(sc[rt][j], 8);
    }
    if (r < 4) {
      const int row = 16 * rt + 4 * q + r;
      float s = (r == 0) ? sc[rt][0] : (r == 1) ? sc[rt][1]
              : (r == 2) ? sc[rt][2] : sc[rt][3];
      float e = (nbase + row < tn) ? __expf(s) : 0.0f;
      evals[rt] = e;
      epart += e;
      if (w == 0) e0[bm0 + row] = e;       // head-0 numerators
    }
  }
  #pragma unroll
  for (int m = 1; m < 64; m <<= 1) epart += __shfl_xor(epart, m);
  if (lane == 0) esum[(size_t)h * NBLK + blk] = epart;

  // ---- pool phase: P[m=lane] = sum over 32 rows of e*mh ----
  {
    float P = 0.f;
    #pragma unroll
    for (int rt = 0; rt < 2; ++rt) {
      #pragma unroll
      for (int rr = 0; rr < 16; ++rr) {
        const int row = 16 * rt + rr;
        const float ev = __shfl(evals[rt], 16 * (rr >> 2) + (rr & 3));
        const int intra = (h * 128 + lane * 2) ^ ((row & 7) << 4);
        P += ev * b2f(*reinterpret_cast<const short*>(mh_base + row * 1024 + intra));
      }
    }
    part[((size_t)h * NBLK + blk) * 64 + lane] = P;
  }
}

// ---------------------------------------------------------------------------
// Kernel 3: finalize. grid 64 = (h,b); 128 chunks per bag.
// ---------------------------------------------------------------------------
__global__ __launch_bounds__(256) void finalize_kernel(
    const float* __restrict__ part, const float* __restrict__ esum,
    const float* __restrict__ e0,
    float* __restrict__ out_feat, float* __restrict__ out_soft) {
  const int h = blockIdx.x >> 3, b = blockIdx.x & 7;
  const int tid = threadIdx.x;

  float Z = 0.f;
  #pragma unroll 8
  for (int c = 0; c < CPB; ++c) Z += esum[(size_t)h * NBLK + b * CPB + c];
  const float invZ = 1.0f / Z;

  if (tid < 64) {
    float s = 0.f;
    #pragma unroll 8
    for (int c = 0; c < CPB; ++c)
      s += part[((size_t)h * NBLK + b * CPB + c) * 64 + tid];
    out_feat[(size_t)b * (NHEAD * DM) + h * DM + tid] = s * invZ;
  }
  if (h == 0) {
    #pragma unroll
    for (int i = 0; i < 16; ++i) {
      const int n = tid + i * 256;
      out_soft[(size_t)b * NINST + n] = e0[(size_t)b * NINST + n] * invZ;
    }
  }
}

// ---------------------------------------------------------------------------
extern "C" void kernel_launch(void* const* d_in, const int* in_sizes, int n_in,
                              void* d_out, int out_size, void* d_ws, size_t ws_size,
                              hipStream_t stream) {
  (void)in_sizes; (void)n_in; (void)out_size; (void)ws_size;
  const float* x      = (const float*)d_in[0];
  const float* WX     = (const float*)d_in[1];
  const float* V      = (const float*)d_in[2];
  const float* W      = (const float*)d_in[3];
  const float* gate_w = (const float*)d_in[4];
  const int* true_num = (const int*)d_in[5];
  float* out = (float*)d_out;

  char* ws = (char*)d_ws;
  short* Wt2  = (short*)ws;  ws += (size_t)(NHEAD * DM + DL) * DIM * 2; //   655,360 B
  short* Vt_f = (short*)ws;  ws += (size_t)DL * DM * 2;                 //    16,384 B
  float* part = (float*)ws;  ws += (size_t)NHEAD * NBLK * 64 * 4;       // 2,097,152 B
  float* esum = (float*)ws;  ws += (size_t)NHEAD * NBLK * 4;            //    32,768 B
  float* e0   = (float*)ws;  ws += (size_t)MTOT * 4;                    //   131,072 B

  prep_weights<<<dim3(145), dim3(256), 0, stream>>>(WX, V, gate_w, Wt2, Vt_f);
  fused_kernel<<<dim3(NBLK), dim3(512), 0, stream>>>(
      x, Wt2, Vt_f, W, true_num, part, esum, e0);
  finalize_kernel<<<dim3(NHEAD * BBAG), dim3(256), 0, stream>>>(
      part, esum, e0, out, out + BBAG * NHEAD * DM);
}

// Round 27
// 64.391 us; speedup vs baseline: 1.0232x; 1.0039x over previous
//
#include <hip/hip_runtime.h>
#include <hip/hip_bf16.h>

#define DIM   512
#define NHEAD 8
#define DM    64
#define DL    128
#define BBAG  8
#define NINST 4096
#define MTOT  (BBAG*NINST)     // 32768 instances
#define BM    32
#define NBLK  (MTOT/BM)        // 1024 fused blocks
#define CPB   (NBLK/BBAG)      // 128 chunks per bag

typedef short   bf16x8 __attribute__((ext_vector_type(8)));
typedef __bf16  bf16v8 __attribute__((ext_vector_type(8)));
typedef float   f32x4  __attribute__((ext_vector_type(4)));
typedef short   s16x4  __attribute__((ext_vector_type(4)));

__device__ __forceinline__ short f2b(float f) {
  __hip_bfloat16 h = __float2bfloat16(f);
  return __builtin_bit_cast(short, h);
}
__device__ __forceinline__ float b2f(short s) {
  __hip_bfloat16 h = __builtin_bit_cast(__hip_bfloat16, s);
  return __bfloat162float(h);
}
__device__ __forceinline__ f32x4 mfma_bf16(bf16x8 a, bf16x8 b, f32x4 c) {
  return __builtin_amdgcn_mfma_f32_16x16x32_bf16(
      __builtin_bit_cast(bf16v8, a), __builtin_bit_cast(bf16v8, b), c, 0, 0, 0);
}
__device__ __forceinline__ float fast_sigmoid(float x) {
  return __builtin_amdgcn_rcpf(1.0f + __expf(-x));
}
__device__ __forceinline__ float fast_tanh(float x) {
  float t = __expf(2.0f * x);
  return 1.0f - 2.0f * __builtin_amdgcn_rcpf(t + 1.0f);
}

// ---------------------------------------------------------------------------
// Kernel 1: build Wt2 (proj B, pre-swizzled slabs) and Vt_f (fragment-packed
// score B). Validated on HW (R16-R26, absmax 7.6e-6).
// ---------------------------------------------------------------------------
__global__ __launch_bounds__(256) void prep_weights(
    const float* __restrict__ WX, const float* __restrict__ V,
    const float* __restrict__ gate_w,
    short* __restrict__ Wt2, short* __restrict__ Vt_f) {
  __shared__ float lds[32 * 129];
  const int bid = blockIdx.x, t = threadIdx.x;

  if (bid < 128) {
    const int h = bid >> 4, ks = bid & 15;
    {
      const int kl = t >> 3, m8 = (t & 7) * 8;
      const float* src = WX + ((size_t)(h * DIM + ks * 32 + kl) * DM + m8);
      #pragma unroll
      for (int j = 0; j < 8; ++j) lds[kl * 129 + m8 + j] = src[j];
    }
    __syncthreads();
    {
      const int m = t >> 2, q = t & 3;
      const int col = h * 64 + m;
      const int q2 = (q + ((col & 15) >> 1)) & 3;
      short* dst = Wt2 + ks * 20480 + col * 32 + q2 * 8;
      #pragma unroll
      for (int j = 0; j < 8; ++j) dst[j] = f2b(lds[(q * 8 + j) * 129 + m]);
    }
  } else if (bid < 144) {
    const int ks = bid - 128;
    #pragma unroll
    for (int rep = 0; rep < 2; ++rep) {
      const int idx = rep * 2048 + t * 8;
      const int kl = idx >> 7, l8 = idx & 127;
      const float* src = gate_w + ((size_t)(ks * 32 + kl) * DL + l8);
      #pragma unroll
      for (int j = 0; j < 8; ++j) lds[kl * 129 + l8 + j] = src[j];
    }
    __syncthreads();
    #pragma unroll
    for (int rep = 0; rep < 2; ++rep) {
      const int piece = rep * 256 + t;
      const int l = piece >> 2, q = piece & 3;
      const int col = 512 + l;
      const int q2 = (q + ((col & 15) >> 1)) & 3;
      short* dst = Wt2 + ks * 20480 + col * 32 + q2 * 8;
      #pragma unroll
      for (int j = 0; j < 8; ++j) dst[j] = f2b(lds[(q * 8 + j) * 129 + l]);
    }
  } else {
    // Vt_f: entry e = (ct*2+half)*64 + lane; holds V[m=half*32+q*8+j][l=16ct+r]
    #pragma unroll
    for (int rep = 0; rep < 4; ++rep) {
      const int e = t + rep * 256;
      const int ct = e >> 7, half = (e >> 6) & 1, lane = e & 63;
      const int r = lane & 15, q = lane >> 4;
      short* dst = Vt_f + (size_t)e * 8;
      #pragma unroll
      for (int j = 0; j < 8; ++j) {
        const int m = half * 32 + q * 8 + j;
        dst[j] = f2b(V[(size_t)m * DL + ct * 16 + r]);
      }
    }
  }
}

// ---------------------------------------------------------------------------
// Kernel 2 (FUSED, BM=32, 2 blocks/CU) — SESSION EMPIRICAL BEST:
// proj GEMM (asm-pinned depth-2 B reg pipeline, counted vmcnt, swizzled
// A-LDS) + score (fragment-packed Vt_f/gate in LDS) + masked softmax
// numerators (registers) + partial pool, all in one kernel; mh never
// touches global memory. 134 us naive -> 64.6 us.
// ---------------------------------------------------------------------------
#define BLOAD(dst, addr) \
  asm volatile("global_load_dwordx4 %0, %1, off" : "=v"(dst) : "v"(addr))

__global__ __launch_bounds__(512, 4) void fused_kernel(
    const float* __restrict__ x, const short* __restrict__ Wt2,
    const short* __restrict__ Vt_f, const float* __restrict__ W,
    const int* __restrict__ true_num,
    float* __restrict__ part, float* __restrict__ esum,
    float* __restrict__ e0) {
  __shared__ alignas(16) short lds[18432];   // 36,864 B
  const int tid = threadIdx.x;
  const int blk = blockIdx.x;
  const int bm0 = blk * BM;
  const int lane = tid & 63;
  const int w = tid >> 6;            // wave 0..7 -> cols [80w,80w+80); head w
  const int r = lane & 15;
  const int q = lane >> 4;           // 0..3
  const int swzs = (q + (r >> 1)) & 3;
  char* lda = reinterpret_cast<char*>(lds);
  char* mh_base = reinterpret_cast<char*>(lds);          // [32][1024B] swizzled
  short* gate_lds = lds + 16384;                         // 16 tiles*64 lanes*4

  const int tn = true_num[blk >> 7];          // bag = blk/128
  const int nbase = bm0 & (NINST - 1);        // row offset within bag

  // ---- phase 1: stage A tile (32 x 512) f32 -> bf16 LDS, swizzled ----
  {
    const int arow = tid >> 4, ap = tid & 15;
    const int aslot = ((ap >> 2) + ((arow & 15) >> 1)) & 3;
    const float* asrc = x + ((size_t)(bm0 + arow) << 9) + ap * 2;
    char* adst = lda + arow * 64 + aslot * 16 + (ap & 3) * 4;
    #pragma unroll
    for (int ks = 0; ks < 16; ++ks) {
      float2 v = *reinterpret_cast<const float2*>(asrc + ks * 32);
      unsigned pk = ((unsigned)(unsigned short)f2b(v.y) << 16) |
                    (unsigned)(unsigned short)f2b(v.x);
      *reinterpret_cast<unsigned*>(adst + ks * 2048) = pk;
    }
  }
  __syncthreads();   // drains prologue vmem; asm ledger starts at 0

  const short* bbase = Wt2 + (80 * w + r) * 32 + swzs * 8;
  bf16x8 bufs[2][5];
  #pragma unroll
  for (int ct = 0; ct < 5; ++ct) BLOAD(bufs[0][ct], bbase + 0 * 20480 + ct * 512);
  #pragma unroll
  for (int ct = 0; ct < 5; ++ct) BLOAD(bufs[1][ct], bbase + 1 * 20480 + ct * 512);

  const int aoff = r * 64 + swzs * 16;
  bf16x8 afb[2][2];
  #pragma unroll
  for (int rt = 0; rt < 2; ++rt)
    afb[0][rt] = *reinterpret_cast<const bf16x8*>(lda + 0 * 2048 + aoff + rt * 1024);

  f32x4 acc[2][5];
  #pragma unroll
  for (int rt = 0; rt < 2; ++rt)
    #pragma unroll
    for (int ct = 0; ct < 5; ++ct) acc[rt][ct] = f32x4{0.f, 0.f, 0.f, 0.f};

  #pragma unroll
  for (int ks = 0; ks < 16; ++ks) {
    // retire B(ks); B(ks+1) stays in flight
    if (ks < 15) asm volatile("s_waitcnt vmcnt(5)" ::: "memory");
    else         asm volatile("s_waitcnt vmcnt(0)" ::: "memory");
    __builtin_amdgcn_sched_barrier(0);

    if (ks + 1 < 16) {
      #pragma unroll
      for (int rt = 0; rt < 2; ++rt)
        afb[(ks + 1) & 1][rt] = *reinterpret_cast<const bf16x8*>(
            lda + (ks + 1) * 2048 + aoff + rt * 1024);
    }
    #pragma unroll
    for (int ct = 0; ct < 5; ++ct)
      #pragma unroll
      for (int rt = 0; rt < 2; ++rt)
        acc[rt][ct] = mfma_bf16(afb[ks & 1][rt], bufs[ks & 1][ct], acc[rt][ct]);
    // refill the just-consumed buffer with B(ks+2) (WAR-safe: issued after reads)
    if (ks + 2 < 16) {
      #pragma unroll
      for (int ct = 0; ct < 5; ++ct)
        BLOAD(bufs[ks & 1][ct], bbase + (ks + 2) * 20480 + ct * 512);
    }
  }

  __syncthreads();   // all A reads done; safe to overwrite with mh/gate

  // ---- epilogue: mh -> swizzled LDS [32][1024B]; gate -> fragment tiles ----
  #pragma unroll
  for (int rt = 0; rt < 2; ++rt) {
    #pragma unroll
    for (int ct = 0; ct < 5; ++ct) {
      const int colbase = 80 * w + 16 * ct;
      if (colbase < NHEAD * DM) {
        const int col = colbase + r;
        #pragma unroll
        for (int j = 0; j < 4; ++j) {
          const int row = 16 * rt + 4 * q + j;
          const int intra = (col * 2) ^ ((row & 7) << 4);
          *reinterpret_cast<short*>(mh_base + row * 1024 + intra) =
              f2b(acc[rt][ct][j]);
        }
      } else {
        const int ltile = 5 * w + ct - 32;
        s16x4 gv;
        gv.x = f2b(fast_sigmoid(acc[rt][ct][0]));
        gv.y = f2b(fast_sigmoid(acc[rt][ct][1]));
        gv.z = f2b(fast_sigmoid(acc[rt][ct][2]));
        gv.w = f2b(fast_sigmoid(acc[rt][ct][3]));
        *reinterpret_cast<s16x4*>(
            gate_lds + ((rt * 8 + ltile) * 64 + lane) * 4) = gv;
      }
    }
  }
  __syncthreads();   // mh + gate complete

  // ---- score phase: wave w = head h = w, 32 rows ----
  const int h = w;
  float wc[8];
  #pragma unroll
  for (int lt = 0; lt < 8; ++lt) wc[lt] = W[(size_t)h * DL + 16 * lt + r];

  bf16x8 a0[2], a1[2];
  #pragma unroll
  for (int rt = 0; rt < 2; ++rt) {
    const int row = 16 * rt + r;
    const int swz = (row & 7) << 4;
    a0[rt] = *reinterpret_cast<const bf16x8*>(
        mh_base + row * 1024 + ((h * 128 + q * 16) ^ swz));
    a1[rt] = *reinterpret_cast<const bf16x8*>(
        mh_base + row * 1024 + ((h * 128 + q * 16 + 64) ^ swz));
  }

  float sc[2][4];
  #pragma unroll
  for (int rt = 0; rt < 2; ++rt)
    #pragma unroll
    for (int j = 0; j < 4; ++j) sc[rt][j] = 0.f;

  #pragma unroll
  for (int lt = 0; lt < 8; ++lt) {
    bf16x8 b0 = *reinterpret_cast<const bf16x8*>(Vt_f + (size_t)(lt * 2) * 512 + lane * 8);
    bf16x8 b1 = *reinterpret_cast<const bf16x8*>(Vt_f + (size_t)(lt * 2 + 1) * 512 + lane * 8);
    #pragma unroll
    for (int rt = 0; rt < 2; ++rt) {
      f32x4 t = f32x4{0.f, 0.f, 0.f, 0.f};
      t = mfma_bf16(a0[rt], b0, t);
      t = mfma_bf16(a1[rt], b1, t);
      s16x4 ga = *reinterpret_cast<const s16x4*>(
          gate_lds + ((rt * 8 + lt) * 64 + lane) * 4);
      #pragma unroll
      for (int j = 0; j < 4; ++j) {
        float g = b2f((j == 0) ? ga.x : (j == 1) ? ga.y : (j == 2) ? ga.z : ga.w);
        sc[rt][j] += fast_tanh(t[j]) * g * wc[lt];
      }
    }
  }

  float evals[2] = {0.f, 0.f};
  float epart = 0.f;
  #pragma unroll
  for (int rt = 0; rt < 2; ++rt) {
    #pragma unroll
    for (int j = 0; j < 4; ++j) {
      sc[rt][j] += __shfl_xor(sc[rt][j], 1);
      sc[rt][j] += __shfl_xor(sc[rt][j], 2);
      sc[rt][j] += __shfl_xor(sc[rt][j], 4);
      sc[rt][j] += __shfl_xor(sc[rt][j], 8);
    }
    if (r < 4) {
      const int row = 16 * rt + 4 * q + r;
      float s = (r == 0) ? sc[rt][0] : (r == 1) ? sc[rt][1]
              : (r == 2) ? sc[rt][2] : sc[rt][3];
      float e = (nbase + row < tn) ? __expf(s) : 0.0f;
      evals[rt] = e;
      epart += e;
      if (w == 0) e0[bm0 + row] = e;       // head-0 numerators
    }
  }
  #pragma unroll
  for (int m = 1; m < 64; m <<= 1) epart += __shfl_xor(epart, m);
  if (lane == 0) esum[(size_t)h * NBLK + blk] = epart;

  // ---- pool phase: P[m=lane] = sum over 32 rows of e*mh ----
  {
    float P = 0.f;
    #pragma unroll
    for (int rt = 0; rt < 2; ++rt) {
      #pragma unroll
      for (int rr = 0; rr < 16; ++rr) {
        const int row = 16 * rt + rr;
        const float ev = __shfl(evals[rt], 16 * (rr >> 2) + (rr & 3));
        const int intra = (h * 128 + lane * 2) ^ ((row & 7) << 4);
        P += ev * b2f(*reinterpret_cast<const short*>(mh_base + row * 1024 + intra));
      }
    }
    part[((size_t)h * NBLK + blk) * 64 + lane] = P;
  }
}

// ---------------------------------------------------------------------------
// Kernel 3: finalize. grid 64 = (h,b); 128 chunks per bag.
// ---------------------------------------------------------------------------
__global__ __launch_bounds__(256) void finalize_kernel(
    const float* __restrict__ part, const float* __restrict__ esum,
    const float* __restrict__ e0,
    float* __restrict__ out_feat, float* __restrict__ out_soft) {
  const int h = blockIdx.x >> 3, b = blockIdx.x & 7;
  const int tid = threadIdx.x;

  float Z = 0.f;
  #pragma unroll 8
  for (int c = 0; c < CPB; ++c) Z += esum[(size_t)h * NBLK + b * CPB + c];
  const float invZ = 1.0f / Z;

  if (tid < 64) {
    float s = 0.f;
    #pragma unroll 8
    for (int c = 0; c < CPB; ++c)
      s += part[((size_t)h * NBLK + b * CPB + c) * 64 + tid];
    out_feat[(size_t)b * (NHEAD * DM) + h * DM + tid] = s * invZ;
  }
  if (h == 0) {
    #pragma unroll
    for (int i = 0; i < 16; ++i) {
      const int n = tid + i * 256;
      out_soft[(size_t)b * NINST + n] = e0[(size_t)b * NINST + n] * invZ;
    }
  }
}

// ---------------------------------------------------------------------------
extern "C" void kernel_launch(void* const* d_in, const int* in_sizes, int n_in,
                              void* d_out, int out_size, void* d_ws, size_t ws_size,
                              hipStream_t stream) {
  (void)in_sizes; (void)n_in; (void)out_size; (void)ws_size;
  const float* x      = (const float*)d_in[0];
  const float* WX     = (const float*)d_in[1];
  const float* V      = (const float*)d_in[2];
  const float* W      = (const float*)d_in[3];
  const float* gate_w = (const float*)d_in[4];
  const int* true_num = (const int*)d_in[5];
  float* out = (float*)d_out;

  char* ws = (char*)d_ws;
  short* Wt2  = (short*)ws;  ws += (size_t)(NHEAD * DM + DL) * DIM * 2; //   655,360 B
  short* Vt_f = (short*)ws;  ws += (size_t)DL * DM * 2;                 //    16,384 B
  float* part = (float*)ws;  ws += (size_t)NHEAD * NBLK * 64 * 4;       // 2,097,152 B
  float* esum = (float*)ws;  ws += (size_t)NHEAD * NBLK * 4;            //    32,768 B
  float* e0   = (float*)ws;  ws += (size_t)MTOT * 4;                    //   131,072 B

  prep_weights<<<dim3(145), dim3(256), 0, stream>>>(WX, V, gate_w, Wt2, Vt_f);
  fused_kernel<<<dim3(NBLK), dim3(512), 0, stream>>>(
      x, Wt2, Vt_f, W, true_num, part, esum, e0);
  finalize_kernel<<<dim3(NHEAD * BBAG), dim3(256), 0, stream>>>(
      part, esum, e0, out, out + BBAG * NHEAD * DM);
}